// Round 5
// baseline (928.661 us; speedup 1.0000x reference)
//
#include <hip/hip_runtime.h>
#include <hip/hip_cooperative_groups.h>

namespace cg = cooperative_groups;

// OLSTM: T=20 frames, N=50000 nodes, K=10000 active peds/frame
// RNN=128, EMB=64, IN=2, OUT=5, G2=16
#define TT   20
#define NN   50000
#define KK   10000
#define RNN  128
#define EMB  64
#define GG2  16
#define NOUT 5
#define MPB  16              // peds per tile (MFMA m-tile)
#define NTHR 256             // 4 waves
#define NTILE (KK / MPB)     // 625 tiles per frame

typedef __attribute__((ext_vector_type(8))) short bf16x8;
typedef __attribute__((ext_vector_type(4))) float f32x4;

__device__ __forceinline__ unsigned short f2b(float x) {  // fp32 -> bf16 bits, RNE
    union { float f; unsigned u; } v; v.f = x;
    return (unsigned short)((v.u + 0x7FFF + ((v.u >> 16) & 1)) >> 16);
}
__device__ __forceinline__ unsigned pack2(float a, float b) {
    return (unsigned)f2b(a) | ((unsigned)f2b(b) << 16);
}
__device__ __forceinline__ float sigf(float x)   { return 1.f / (1.f + __expf(-x)); }
__device__ __forceinline__ float tanh_f(float x) { return 2.f / (1.f + __expf(-2.f * x)) - 1.f; }

struct Params {
    const float* input_data; const float* grids;
    const float* h0; const float* c0;
    const int*   active_idx;
    const float* W_in;  const float* b_in;
    const float* W_obs; const float* b_obs;
    const float* W_ih;  const float* b_ih;
    const float* W_hh;  const float* b_hh;
    const float* W_out; const float* b_out;
    float* outputs; float* h_all; float* c_all;
    unsigned short* Wt; float* biasp; int* win;   // win: 2*NN ints (ping-pong)
};

struct Smem {
    unsigned short uS[MPB][264];  // [ie(64) te(64) h(128)] bf16
    float cS[MPB][132];           // c state; reused in-place as h_new
    float gS[MPB][GG2];
    int s_idx[MPB];
    int s_win[MPB];
};

// bf16 transposed+permuted weights Wt[cp][k] (512x256) + fused bias (round-3 proven):
// cp = 64*wq + 16*gate + cl  ->  orig col = 128*gate + 16*wq + cl.
// A 4-wave consumer taking cp in [128w,128w+128) gets gates i,f,g,o for
// r = 32w + 16*rg + cl with ni=4*rg+gate — lane-local LSTM (algebraically identical table).
__global__ __launch_bounds__(256) void prep_kernel(
    const float* __restrict__ Wih, const float* __restrict__ Whh,
    const float* __restrict__ bih, const float* __restrict__ bhh,
    unsigned short* __restrict__ Wt, float* __restrict__ biasp)
{
    int cp = blockIdx.x;       // 0..511 (permuted col)
    int k  = threadIdx.x;      // 0..255
    int wq = cp >> 6, rem = cp & 63, gate = rem >> 4, cl = rem & 15;
    int oc = 128 * gate + 16 * wq + cl;
    float v = (k < 128) ? Wih[k * 512 + oc] : Whh[(k - 128) * 512 + oc];
    Wt[cp * 256 + k] = f2b(v);
    if (k == 0) biasp[cp] = bih[oc] + bhh[oc];
}

// Copy initial h/c into d_out state region; winner pass-1 for frame 0 (parity 0).
__global__ __launch_bounds__(256) void init_kernel(
    const float* __restrict__ h0, const float* __restrict__ c0,
    const int* __restrict__ idx0,
    float* __restrict__ h_all, float* __restrict__ c_all, int* __restrict__ win0)
{
    int stride = gridDim.x * blockDim.x;
    int i = blockIdx.x * blockDim.x + threadIdx.x;
    for (int p = i; p < NN * RNN; p += stride) { h_all[p] = h0[p]; c_all[p] = c0[p]; }
    for (int p = i; p < KK; p += stride) atomicMax(&win0[idx0[p]], p);
}

// One 16-ped tile of one frame. Cross-frame shared data (h/c state, win flags)
// moves via relaxed AGENT-scope atomics -> coherent at the device coherence point
// regardless of XCD, independent of fence lowering.
__device__ __forceinline__ void frame_body(const Params& P, Smem& S, int t, int tile, int has_next) {
    const int tid = threadIdx.x;
    const int k0  = tile * MPB;
    int* win_cur = P.win + (t & 1) * NN;
    int* win_nxt = P.win + ((t + 1) & 1) * NN;

    // ---- phase 0: winner flags + pass-1 atomics for frame t+1 ----
    if (tid < MPB) {
        int k = k0 + tid;
        if (has_next)
            atomicMax(&win_nxt[P.active_idx[(t + 1) * KK + k]], (t + 1) * KK + k);
        int node = P.active_idx[t * KK + k];
        S.s_idx[tid] = node;
        int wtag = __hip_atomic_load(&win_cur[node], __ATOMIC_RELAXED, __HIP_MEMORY_SCOPE_AGENT);
        S.s_win[tid] = (wtag == t * KK + k) ? 1 : 0;
    }
    {   // stage grid rows (coalesced 1 KB)
        int m = tid >> 4, g = tid & 15;
        S.gS[m][g] = P.grids[((size_t)t * KK + k0 + m) * GG2 + g];
    }
    __syncthreads();

    // ---- gather h (->bf16) + c (fp32): 16 threads/ped, agent-coherent dword loads ----
    {
        int m = tid >> 4, l = tid & 15;
        int node = S.s_idx[m];
        const float* hp = P.h_all + (size_t)node * RNN + l * 8;
        const float* cp = P.c_all + (size_t)node * RNN + l * 8;
        float hv[8], cv[8];
        #pragma unroll
        for (int j = 0; j < 8; ++j)
            hv[j] = __hip_atomic_load(hp + j, __ATOMIC_RELAXED, __HIP_MEMORY_SCOPE_AGENT);
        #pragma unroll
        for (int j = 0; j < 8; ++j)
            cv[j] = __hip_atomic_load(cp + j, __ATOMIC_RELAXED, __HIP_MEMORY_SCOPE_AGENT);
        unsigned* du = (unsigned*)&S.uS[m][128 + l * 8];
        #pragma unroll
        for (int j = 0; j < 4; ++j) du[j] = pack2(hv[2 * j], hv[2 * j + 1]);
        #pragma unroll
        for (int j = 0; j < 8; ++j) S.cS[m][l * 8 + j] = cv[j];
    }
    // ---- embeddings: 16 threads/ped, 4 cols each ----
    {
        int m = tid >> 4, e0 = (tid & 15) * 4;
        int node = S.s_idx[m];
        float x0 = P.input_data[((size_t)t * NN + node) * 2 + 0];
        float x1 = P.input_data[((size_t)t * NN + node) * 2 + 1];
        float iv[4], tv[4];
        #pragma unroll
        for (int j = 0; j < 4; ++j) {
            int e = e0 + j;
            iv[j] = fmaxf(fmaf(x0, P.W_in[e], fmaf(x1, P.W_in[64 + e], P.b_in[e])), 0.f);
            tv[j] = P.b_obs[e];
        }
        #pragma unroll
        for (int g = 0; g < GG2; ++g) {
            float gv = S.gS[m][g];
            #pragma unroll
            for (int j = 0; j < 4; ++j) tv[j] = fmaf(gv, P.W_obs[g * EMB + e0 + j], tv[j]);
        }
        unsigned* di = (unsigned*)&S.uS[m][e0];
        unsigned* dt = (unsigned*)&S.uS[m][64 + e0];
        di[0] = pack2(iv[0], iv[1]); di[1] = pack2(iv[2], iv[3]);
        dt[0] = pack2(fmaxf(tv[0], 0.f), fmaxf(tv[1], 0.f));
        dt[1] = pack2(fmaxf(tv[2], 0.f), fmaxf(tv[3], 0.f));
    }
    __syncthreads();

    // ---- gates GEMM via MFMA: wave w covers permuted cols [128w, 128w+128) ----
    const int w = tid >> 6, lane = tid & 63;
    const int cl = lane & 15, kq = lane >> 4;
    f32x4 acc[8];
    #pragma unroll
    for (int ni = 0; ni < 8; ++ni) {
        float bv = P.biasp[128 * w + 16 * ni + cl];
        acc[ni] = (f32x4){bv, bv, bv, bv};
    }
    const unsigned short* Wb = P.Wt + ((size_t)(128 * w + cl)) * 256 + kq * 8;
    #pragma unroll
    for (int ks = 0; ks < 8; ++ks) {
        const int kk = ks * 32;
        bf16x8 a = *(const bf16x8*)&S.uS[cl][kk + kq * 8];
        #pragma unroll
        for (int ni = 0; ni < 8; ++ni) {
            bf16x8 bf = *(const bf16x8*)(Wb + (size_t)ni * 16 * 256 + kk);
            acc[ni] = __builtin_amdgcn_mfma_f32_16x16x32_bf16(a, bf, acc[ni], 0, 0, 0);
        }
    }

    // ---- LSTM: lane-local i,f,g,o; ped m = 4*kq+reg, rnn unit r = 32w+16rg+cl ----
    #pragma unroll
    for (int rg = 0; rg < 2; ++rg) {
        #pragma unroll
        for (int reg = 0; reg < 4; ++reg) {
            float iv = acc[4 * rg + 0][reg], fv = acc[4 * rg + 1][reg];
            float gv = acc[4 * rg + 2][reg], ov = acc[4 * rg + 3][reg];
            int m = 4 * kq + reg;
            int r = 32 * w + 16 * rg + cl;
            float cn = fmaf(sigf(fv), S.cS[m][r], sigf(iv) * tanh_f(gv));
            float hv = sigf(ov) * tanh_f(cn);
            S.cS[m][r] = hv;  // exclusive (m,r) per lane: safe in-place h_new
            if (S.s_win[m]) { // winners-only state update, agent-coherent stores
                int node = S.s_idx[m];
                __hip_atomic_store(&P.h_all[(size_t)node * RNN + r], hv,
                                   __ATOMIC_RELAXED, __HIP_MEMORY_SCOPE_AGENT);
                __hip_atomic_store(&P.c_all[(size_t)node * RNN + r], cn,
                                   __ATOMIC_RELAXED, __HIP_MEMORY_SCOPE_AGENT);
            }
        }
    }
    __syncthreads();  // h_new (in cS) visible block-wide

    // ---- out projection (winners only), h_new from LDS ----
    if (tid < MPB * NOUT) {
        int m = tid / NOUT, o = tid - m * NOUT;
        if (S.s_win[m]) {
            const float* hp = S.cS[m];
            float a0 = P.b_out[o], a1 = 0.f, a2 = 0.f, a3 = 0.f;
            #pragma unroll 4
            for (int r = 0; r < RNN; r += 4) {
                a0 = fmaf(hp[r],     P.W_out[(r)     * NOUT + o], a0);
                a1 = fmaf(hp[r + 1], P.W_out[(r + 1) * NOUT + o], a1);
                a2 = fmaf(hp[r + 2], P.W_out[(r + 2) * NOUT + o], a2);
                a3 = fmaf(hp[r + 3], P.W_out[(r + 3) * NOUT + o], a3);
            }
            P.outputs[((size_t)t * NN + S.s_idx[m]) * NOUT + o] = (a0 + a1) + (a2 + a3);
        }
    }
    __syncthreads();  // LDS safe to reuse for the next tile
}

// Persistent cooperative kernel: grid-stride over tiles, grid.sync between frames.
__global__ __launch_bounds__(NTHR) void persist_kernel(Params P) {
    cg::grid_group gridg = cg::this_grid();
    __shared__ Smem S;
    for (int t = 0; t < TT; ++t) {
        for (int tile = blockIdx.x; tile < NTILE; tile += gridDim.x)
            frame_body(P, S, t, tile, (t + 1 < TT) ? 1 : 0);
        __threadfence();   // drain stores before barrier arrival
        gridg.sync();
        __threadfence();   // order next frame's loads after the barrier
    }
}

// Fallback: one frame per launch (kernel boundaries provide global visibility).
__global__ __launch_bounds__(NTHR) void step_kernel(Params P, int t, int has_next) {
    __shared__ Smem S;
    frame_body(P, S, t, blockIdx.x, has_next);
}

extern "C" void kernel_launch(void* const* d_in, const int* in_sizes, int n_in,
                              void* d_out, int out_size, void* d_ws, size_t ws_size,
                              hipStream_t stream) {
    Params P;
    P.input_data = (const float*)d_in[0];
    P.grids      = (const float*)d_in[1];
    P.h0         = (const float*)d_in[2];
    P.c0         = (const float*)d_in[3];
    P.active_idx = (const int*)d_in[4];
    P.W_in  = (const float*)d_in[5];
    P.b_in  = (const float*)d_in[6];
    P.W_obs = (const float*)d_in[7];
    P.b_obs = (const float*)d_in[8];
    P.W_ih  = (const float*)d_in[9];
    P.b_ih  = (const float*)d_in[10];
    P.W_hh  = (const float*)d_in[11];
    P.b_hh  = (const float*)d_in[12];
    P.W_out = (const float*)d_in[13];
    P.b_out = (const float*)d_in[14];

    // d_out: outputs[T*N*5] | h_fin[N*128] | c_fin[N*128] — state lives in place.
    P.outputs = (float*)d_out;
    P.h_all   = P.outputs + (size_t)TT * NN * NOUT;
    P.c_all   = P.h_all + (size_t)NN * RNN;

    // d_ws: win[2*N] ints | Wt bf16 512x256 | biasp[512]
    P.win   = (int*)d_ws;
    P.Wt    = (unsigned short*)((char*)d_ws + (size_t)2 * NN * sizeof(int));
    P.biasp = (float*)((char*)d_ws + (size_t)2 * NN * sizeof(int) + 512 * 256 * sizeof(unsigned short));

    hipMemsetAsync(P.outputs, 0, (size_t)TT * NN * NOUT * sizeof(float), stream);
    hipMemsetAsync(P.win, 0xFF, (size_t)2 * NN * sizeof(int), stream);  // -1 everywhere
    prep_kernel<<<512, 256, 0, stream>>>(P.W_ih, P.W_hh, P.b_ih, P.b_hh, P.Wt, P.biasp);
    init_kernel<<<1024, 256, 0, stream>>>(P.h0, P.c0, P.active_idx, P.h_all, P.c_all, P.win);

    // Size the cooperative grid from the runtime's own occupancy arithmetic.
    int maxB = 0;
    hipError_t qe = hipOccupancyMaxActiveBlocksPerMultiprocessor(&maxB, persist_kernel, NTHR, 0);
    int ncu = 0, dev = 0;
    hipGetDevice(&dev);
    if (hipDeviceGetAttribute(&ncu, hipDeviceAttributeMultiprocessorCount, dev) != hipSuccess || ncu <= 0)
        ncu = 256;
    hipError_t le = hipErrorUnknown;
    if (qe == hipSuccess && maxB >= 1) {
        int grid = maxB * ncu;
        if (grid > NTILE) grid = NTILE;
        void* kargs[] = { (void*)&P };
        le = hipLaunchCooperativeKernel((const void*)persist_kernel, dim3(grid), dim3(NTHR),
                                        kargs, 0, stream);
    }
    if (le != hipSuccess) {
        (void)hipGetLastError();  // clear; take the proven per-frame path
        for (int t = 0; t < TT; ++t)
            step_kernel<<<NTILE, NTHR, 0, stream>>>(P, t, (t + 1 < TT) ? 1 : 0);
    }
}